// Round 2
// baseline (194.030 us; speedup 1.0000x reference)
//
#include <hip/hip_runtime.h>
#include <math.h>
#include <float.h>

#define NBATCH 4
#define NH 8192
#define NO 16384
#define NQ 1024
#define MAX_ITER 40
#define TOL_F 1e-4f
#define EPS_F 1e-10f

#define QPB 4                 // queries per block
#define SLICES 64             // target slices per query
#define NTHREADS (QPB * SLICES)   // 256
#define HCHUNK (NH / SLICES)  // 128
#define OCHUNK (NO / SLICES)  // 256

__device__ __forceinline__ void combine(float& bs, int& bi, float s, int i) {
    if (s < bs || (s == bs && i < bi)) { bs = s; bi = i; }
}

template<bool PACKED>
__device__ __forceinline__ float4 load_pt(const float4* __restrict__ p4,
                                          const float* __restrict__ praw, int i) {
    if (PACKED) {
        return p4[i];
    } else {
        float x = praw[3 * i], y = praw[3 * i + 1], z = praw[3 * i + 2];
        return make_float4(x, y, z, 0.5f * (x * x + y * y + z * z));
    }
}

// Repack [N][3] clouds into [N] float4 with w = 0.5*|t|^2 (for 3-FMA score).
__global__ void repack_kernel(const float* __restrict__ obj, const float* __restrict__ hand,
                              float4* __restrict__ hand4, float4* __restrict__ obj4) {
    int i = blockIdx.x * 256 + threadIdx.x;
    if (i < NBATCH * NH) {
        float x = hand[3 * i], y = hand[3 * i + 1], z = hand[3 * i + 2];
        hand4[i] = make_float4(x, y, z, 0.5f * (x * x + y * y + z * z));
    } else {
        int j = i - NBATCH * NH;
        if (j < NBATCH * NO) {
            float x = obj[3 * j], y = obj[3 * j + 1], z = obj[3 * j + 2];
            obj4[j] = make_float4(x, y, z, 0.5f * (x * x + y * y + z * z));
        }
    }
}

// Per-batch centers + radius_val: cen[b] = {cx, cy, cz, radius_val}
__global__ void centers_kernel(const float* __restrict__ obj, const float* __restrict__ hand,
                               float* __restrict__ cen) {
    const int b = blockIdx.x, t = threadIdx.x;
    const float* hp = hand + (size_t)b * NH * 3;
    const float* op = obj + (size_t)b * NO * 3;
    float hx = 0, hy = 0, hz = 0, ox = 0, oy = 0, oz = 0;
    for (int i = t; i < NH; i += 256) { hx += hp[3*i]; hy += hp[3*i+1]; hz += hp[3*i+2]; }
    for (int i = t; i < NO; i += 256) { ox += op[3*i]; oy += op[3*i+1]; oz += op[3*i+2]; }
    __shared__ float red[6][256];
    red[0][t] = hx; red[1][t] = hy; red[2][t] = hz;
    red[3][t] = ox; red[4][t] = oy; red[5][t] = oz;
    __syncthreads();
    for (int s = 128; s > 0; s >>= 1) {
        if (t < s) {
            #pragma unroll
            for (int k = 0; k < 6; ++k) red[k][t] += red[k][t + s];
        }
        __syncthreads();
    }
    if (t == 0) {
        float hcx = red[0][0] / NH, hcy = red[1][0] / NH, hcz = red[2][0] / NH;
        float ocx = red[3][0] / NO, ocy = red[4][0] / NO, ocz = red[5][0] / NO;
        float dx = hcx - ocx, dy = hcy - ocy, dz = hcz - ocz;
        cen[b * 4 + 0] = 0.5f * (hcx + ocx);
        cen[b * 4 + 1] = 0.5f * (hcy + ocy);
        cen[b * 4 + 2] = 0.5f * (hcz + ocz);
        cen[b * 4 + 3] = 0.8f * sqrtf(dx * dx + dy * dy + dz * dz) + 0.05f;
    }
}

template<bool PACKED>
__global__ __launch_bounds__(NTHREADS)
void ibs_kernel(const float* __restrict__ obj, const float* __restrict__ hand,
                const float* __restrict__ uvw, const float* __restrict__ cen,
                const float4* __restrict__ hand4, const float4* __restrict__ obj4,
                float* __restrict__ out) {
    const int t = threadIdx.x;
    const int ql = t & (QPB - 1);        // query within block
    const int sl = t >> 2;               // target slice (0..63)
    const int gq = blockIdx.x * QPB + ql; // global query id
    const int b = gq >> 10;              // batch (NQ = 1024)

    const float4* hb4 = hand4 + (size_t)b * NH;
    const float4* ob4 = obj4 + (size_t)b * NO;
    const float* hbr = hand + (size_t)b * NH * 3;
    const float* obr = obj + (size_t)b * NO * 3;

    // ---- initial point (replicated across the query's 64 threads) ----
    const float cx = cen[b*4+0], cy = cen[b*4+1], cz = cen[b*4+2], rv = cen[b*4+3];
    const float u = uvw[gq*3+0], v = uvw[gq*3+1], w = uvw[gq*3+2];
    const float r = rv * powf(u, 1.0f / 3.0f);
    const float ctheta = 2.0f * v - 1.0f;
    const float stheta = sqrtf(fmaxf(0.0f, 1.0f - ctheta * ctheta));
    const float phi = 6.283185307179586477f * w;
    float sp, cp;
    sincosf(phi, &sp, &cp);
    float px = cx + r * stheta * cp;
    float py = cy + r * stheta * sp;
    float pz = cz + r * ctheta;

    __shared__ float rsc[2][4][QPB];
    __shared__ int   rix[2][4][QPB];

    for (int it = 0; it < MAX_ITER; ++it) {
        const float nqx = -px, nqy = -py, nqz = -pz;

        // ---- scan own slice of hand cloud: key = 0.5|t|^2 - p.t ----
        float hs = FLT_MAX; int hi = 0;
        {
            const int base = sl * HCHUNK;
            const float4* p4 = hb4 + base;
            const float* pr = hbr + 3 * base;
            #pragma unroll 8
            for (int i = 0; i < HCHUNK; ++i) {
                float4 tp = load_pt<PACKED>(p4, pr, i);
                float s = fmaf(tp.x, nqx, fmaf(tp.y, nqy, fmaf(tp.z, nqz, tp.w)));
                if (s < hs) { hs = s; hi = i; }
            }
            hi += base;
        }
        // ---- scan own slice of obj cloud ----
        float osb = FLT_MAX; int oi = 0;
        {
            const int base = sl * OCHUNK;
            const float4* p4 = ob4 + base;
            const float* pr = obr + 3 * base;
            #pragma unroll 8
            for (int i = 0; i < OCHUNK; ++i) {
                float4 tp = load_pt<PACKED>(p4, pr, i);
                float s = fmaf(tp.x, nqx, fmaf(tp.y, nqy, fmaf(tp.z, nqz, tp.w)));
                if (s < osb) { osb = s; oi = i; }
            }
            oi += base;
        }

        // ---- wave-level argmin across slices (xor 4,8,16,32 keeps ql) ----
        #pragma unroll
        for (int m = QPB; m < 64; m <<= 1) {
            float s2 = __shfl_xor(hs, m, 64); int i2 = __shfl_xor(hi, m, 64);
            combine(hs, hi, s2, i2);
            float s3 = __shfl_xor(osb, m, 64); int i3 = __shfl_xor(oi, m, 64);
            combine(osb, oi, s3, i3);
        }
        const int wv = t >> 6;
        if ((t & 63) < QPB) {
            rsc[0][wv][ql] = hs;  rix[0][wv][ql] = hi;
            rsc[1][wv][ql] = osb; rix[1][wv][ql] = oi;
        }
        __syncthreads();
        float hbs = rsc[0][0][ql]; int hbi = rix[0][0][ql];
        float obs = rsc[1][0][ql]; int obi = rix[1][0][ql];
        #pragma unroll
        for (int wv2 = 1; wv2 < 4; ++wv2) {
            combine(hbs, hbi, rsc[0][wv2][ql], rix[0][wv2][ql]);
            combine(obs, obi, rsc[1][wv2][ql], rix[1][wv2][ql]);
        }

        // ---- exact distances + normals for the winners ----
        float4 hp = load_pt<PACKED>(hb4, hbr, hbi);
        float4 op = load_pt<PACKED>(ob4, obr, obi);
        float hvx = hp.x - px, hvy = hp.y - py, hvz = hp.z - pz;
        float ovx = op.x - px, ovy = op.y - py, ovz = op.z - pz;
        float hd = sqrtf(hvx*hvx + hvy*hvy + hvz*hvz);
        float od = sqrtf(ovx*ovx + ovy*ovy + ovz*ovz);
        float rh = 1.0f / (hd + EPS_F);
        float ro = 1.0f / (od + EPS_F);
        float hnx = hvx*rh, hny = hvy*rh, hnz = hvz*rh;
        float onx = ovx*ro, ony = ovy*ro, onz = ovz*ro;

        float sg = hd - od;
        float as = fabsf(sg);

        // all queries in block frozen -> remaining iterations are exact no-ops
        if (__syncthreads_and(as < TOL_F)) break;

        float mask = (as >= TOL_F) ? 1.0f : 0.0f;
        float dt = hnx*onx + hny*ony + hnz*onz;
        bool pos = (sg >= 0.0f);
        float denom = pos ? (hd - od * dt) : (od - hd * dt);
        float wgt = 0.5f * (hd + od) / (denom + EPS_F);
        float mv = wgt * as * mask;
        float dxd = pos ? hnx : onx;
        float dyd = pos ? hny : ony;
        float dzd = pos ? hnz : onz;
        px += mv * dxd;
        py += mv * dyd;
        pz += mv * dzd;
    }

    if (sl == 0) {
        out[gq*3+0] = px;
        out[gq*3+1] = py;
        out[gq*3+2] = pz;
    }
}

extern "C" void kernel_launch(void* const* d_in, const int* in_sizes, int n_in,
                              void* d_out, int out_size, void* d_ws, size_t ws_size,
                              hipStream_t stream) {
    const float* obj  = (const float*)d_in[0];
    const float* hand = (const float*)d_in[1];
    const float* uvw  = (const float*)d_in[2];
    float* out = (float*)d_out;
    float* ws  = (float*)d_ws;

    float* cen = ws;                             // 16 floats
    float4* hand4 = (float4*)(ws + 16);          // [NBATCH*NH]
    float4* obj4  = hand4 + NBATCH * NH;         // [NBATCH*NO]
    const size_t need = (16 + 4ull * NBATCH * NH + 4ull * NBATCH * NO) * sizeof(float);

    centers_kernel<<<NBATCH, 256, 0, stream>>>(obj, hand, cen);

    const int nblocks = NBATCH * NQ / QPB;       // 1024
    if (ws_size >= need) {
        int total = NBATCH * (NH + NO);
        repack_kernel<<<(total + 255) / 256, 256, 0, stream>>>(obj, hand, hand4, obj4);
        ibs_kernel<true><<<nblocks, NTHREADS, 0, stream>>>(obj, hand, uvw, cen, hand4, obj4, out);
    } else {
        ibs_kernel<false><<<nblocks, NTHREADS, 0, stream>>>(obj, hand, uvw, cen, nullptr, nullptr, out);
    }
}